// Round 18
// baseline (221.281 us; speedup 1.0000x reference)
//
#include <hip/hip_runtime.h>
#include <hip/hip_fp16.h>
#include <math.h>

#define N_NODES 50000
#define N_EDGES 800000
#define NUM_GRAPHS 256
#define C_IN 64
#define C_H 128
#define D_COUNT 9
#define LRELU_SLOPE 0.01f
#define TAB_BINS 8192
#define TAB_SCALE 1024.0f                  // bins per unit distance, covers d in [0,8)
#define WEDGES 64                          // edges per wave
#define NCHUNK (N_EDGES / WEDGES)          // 12500 wave-chunks
#define NAGG (NCHUNK / 4)                  // 3125 aggregate blocks
#define NBUCK ((N_NODES + 255) / 256)      // 196 coarse buckets (col>>8)
#define REGION_CAP 6144
#define SCAT_BLK_EDGES 2048
// setup_kernel grid partition
#define TBLK (TAB_BINS * 64 / 256)         // 2048 blocks per radial table
#define WNBLK 8                            // 8 blocks per Wn fragment-swizzle (2048 uint4)
#define ZBLK 1024                          // agg zero (grid-stride)
#define LIN0BLK ((N_NODES + 31) / 32)      // 1563 lin0 tiles
#define OUTZBLK 32                         // d_out zero
#define OFF1 (3 * TBLK)                    // 6144
#define OFF2 (OFF1 + 3 * WNBLK)            // 6168
#define OFF3 (OFF2 + ZBLK)                 // 7192
#define OFF4 (OFF3 + LIN0BLK)              // 8755
#define OFF5 (OFF4 + OUTZBLK)              // 8787
#define SETUP_GRID (OFF5 + 1)              // +1 block: bcur zero

typedef _Float16 half8_t __attribute__((ext_vector_type(8)));
typedef float f32x4_t __attribute__((ext_vector_type(4)));

__device__ __forceinline__ float fast_rcp(float x) { return __builtin_amdgcn_rcpf(x); }
__device__ __forceinline__ __half2 u2h2(unsigned int u) { return __builtin_bit_cast(__half2, u); }
__device__ __forceinline__ unsigned int h22u(__half2 h) { return __builtin_bit_cast(unsigned int, h); }

__device__ __forceinline__ void atomic_pk_add_h2(unsigned int* addr, unsigned int val) {
    asm volatile("global_atomic_pk_add_f16 %0, %1, off"
                 :: "v"(addr), "v"(val) : "memory");
}

// ---------------- setup: tables + Wn frag-swizzle + agg zero + lin0 + out zero + bcur ------
__global__ __launch_bounds__(256) void setup_kernel(
        const float* __restrict__ Wc1, const float* __restrict__ bc1,
        const float* __restrict__ Wc2, const float* __restrict__ bc2,
        const float* __restrict__ Wc3, const float* __restrict__ bc3,
        const float* __restrict__ Wn1, const float* __restrict__ Wn2,
        const float* __restrict__ Wn3,
        const float* __restrict__ x, const float* __restrict__ Wl,
        const float* __restrict__ bl,
        unsigned int* __restrict__ tabh, unsigned int* __restrict__ Wnh,
        uint4* __restrict__ aggz, unsigned int* __restrict__ hhf,
        uint4* __restrict__ outz, int* __restrict__ bcur) {
    __shared__ float xs[32][C_IN];
    const int b = blockIdx.x;
    const int t = threadIdx.x;
    if (b < OFF1) {
        const int l = b / TBLK;
        const float* Wc = (l == 0) ? Wc1 : (l == 1) ? Wc2 : Wc3;
        const float* bc = (l == 0) ? bc1 : (l == 1) ? bc2 : bc3;
        const int idx = (b - l * TBLK) * 256 + t;
        const int lane = idx & 63;
        const int bin = idx >> 6;
        const float d = ((float)bin + 0.5f) * (1.0f / TAB_SCALE);
        float v[2];
#pragma unroll
        for (int p = 0; p < 2; ++p) {
            const int c = 2 * lane + p;
            float a = bc[c];
#pragma unroll
            for (int k = 0; k < D_COUNT; ++k) {
                const float u = (d - 0.75f * (float)k) * 1.5f;  // mu=0.75k, 1/sigma=1.5
                a = fmaf(__expf(-u * u), Wc[k * C_H + c], a);
            }
            v[p] = a * fast_rcp(1.0f + __expf(-a));
        }
        tabh[(size_t)l * TAB_BINS * 64 + idx] = h22u(__floats2half2_rn(v[0], v[1]));
    } else if (b < OFF2) {
        // Wn -> MFMA B-fragment order
        const int bb = b - OFF1;
        const int l = bb / WNBLK;
        const float* Wn = (l == 0) ? Wn1 : (l == 1) ? Wn2 : Wn3;
        const int idx = (bb - l * WNBLK) * 256 + t;   // 0..2047
        const int lane = idx & 63;
        const int tile = idx >> 6;                    // 0..31
        const int kc = tile >> 3, ct = tile & 7;
        const int q = lane >> 4, r = lane & 15;
        half8_t v;
#pragma unroll
        for (int j = 0; j < 8; ++j)
            v[j] = (_Float16)Wn[(size_t)(kc * 32 + 8 * q + j) * C_H + ct * 16 + r];
        ((uint4*)Wnh)[(size_t)l * 2048 + idx] = __builtin_bit_cast(uint4, v);
    } else if (b < OFF3) {
        const int n16 = N_NODES * 16;
        const int stride = ZBLK * 256;
        for (int i = (b - OFF2) * 256 + t; i < n16; i += stride)
            aggz[i] = make_uint4(0u, 0u, 0u, 0u);
    } else if (b < OFF4) {
        // lin0: hhf = half2(silu(x @ Wl + bl))
        const int node0 = (b - OFF3) * 32;
        for (int i = t * 4; i < 32 * C_IN; i += 256 * 4) {
            const int n = i >> 6;
            const int c = i & 63;
            if (node0 + n < N_NODES)
                *(float4*)&xs[n][c] = *(const float4*)&x[(size_t)(node0 + n) * C_IN + c];
        }
        __syncthreads();
        const int wv = t >> 6;
        const int lane = t & 63;
        const int nb = wv * 8;
        const float2 b2 = *(const float2*)&bl[2 * lane];
        float2 acc[8];
#pragma unroll
        for (int n = 0; n < 8; ++n) acc[n] = b2;
        for (int k = 0; k < C_IN; k += 4) {
            const float2 w0 = *(const float2*)&Wl[(size_t)(k + 0) * C_H + 2 * lane];
            const float2 w1 = *(const float2*)&Wl[(size_t)(k + 1) * C_H + 2 * lane];
            const float2 w2 = *(const float2*)&Wl[(size_t)(k + 2) * C_H + 2 * lane];
            const float2 w3 = *(const float2*)&Wl[(size_t)(k + 3) * C_H + 2 * lane];
#pragma unroll
            for (int n = 0; n < 8; ++n) {
                const float4 sv = *(const float4*)&xs[nb + n][k];
                acc[n].x = fmaf(sv.x, w0.x, acc[n].x); acc[n].y = fmaf(sv.x, w0.y, acc[n].y);
                acc[n].x = fmaf(sv.y, w1.x, acc[n].x); acc[n].y = fmaf(sv.y, w1.y, acc[n].y);
                acc[n].x = fmaf(sv.z, w2.x, acc[n].x); acc[n].y = fmaf(sv.z, w2.y, acc[n].y);
                acc[n].x = fmaf(sv.w, w3.x, acc[n].x); acc[n].y = fmaf(sv.w, w3.y, acc[n].y);
            }
        }
#pragma unroll
        for (int n = 0; n < 8; ++n) {
            const int node = node0 + nb + n;
            if (node < N_NODES) {
                const float ax = acc[n].x, ay = acc[n].y;
                const float sx = ax * fast_rcp(1.0f + __expf(-ax));
                const float sy = ay * fast_rcp(1.0f + __expf(-ay));
                hhf[(size_t)node * 64 + lane] = h22u(__floats2half2_rn(sx, sy));
            }
        }
    } else if (b < OFF5) {
        const int n16 = NUM_GRAPHS * C_H / 4;
        const int stride = OUTZBLK * 256;
        for (int i = (b - OFF4) * 256 + t; i < n16; i += stride)
            outz[i] = make_uint4(0u, 0u, 0u, 0u);
    } else {
        if (t < NBUCK) bcur[t] = 0;
    }
}

// ---------------- bucketed CSR build ---------------------------------------------------------
__global__ __launch_bounds__(256) void bscatter_kernel(
        const int* __restrict__ row, const int* __restrict__ col,
        const float* __restrict__ pos, int* __restrict__ bcur, uint2* __restrict__ ebuf) {
    __shared__ int lhist[NBUCK];
    __shared__ int lcur[NBUCK];
    const int t = threadIdx.x;
    const int e0 = blockIdx.x * SCAT_BLK_EDGES;
    for (int i = t; i < NBUCK; i += 256) lhist[i] = 0;
    __syncthreads();

    int myb[8];
    uint2 myrec[8];
#pragma unroll
    for (int s = 0; s < 8; ++s) {
        const int e = e0 + s * 256 + t;
        if (e < N_EDGES) {
            const int r = row[e];
            const int c = col[e];
            const float dx = pos[r * 3 + 0] - pos[c * 3 + 0];
            const float dy = pos[r * 3 + 1] - pos[c * 3 + 1];
            const float dz = pos[r * 3 + 2] - pos[c * 3 + 2];
            const float d = sqrtf(dx * dx + dy * dy + dz * dz);
            int bin = (int)(d * TAB_SCALE);
            bin = bin < TAB_BINS - 1 ? bin : TAB_BINS - 1;
            myb[s] = c >> 8;
            myrec[s] = make_uint2((unsigned int)r | ((unsigned int)c << 16),
                                  (unsigned int)bin);
            atomicAdd(&lhist[myb[s]], 1);
        } else {
            myb[s] = -1;
        }
    }
    __syncthreads();
    for (int i = t; i < NBUCK; i += 256)
        lcur[i] = (lhist[i] > 0) ? atomicAdd(&bcur[i], lhist[i]) : 0;
    __syncthreads();
#pragma unroll
    for (int s = 0; s < 8; ++s) {
        if (myb[s] >= 0) {
            const int p = atomicAdd(&lcur[myb[s]], 1);
            ebuf[(size_t)myb[s] * REGION_CAP + p] = myrec[s];
        }
    }
}

__global__ __launch_bounds__(256) void bsort_kernel(
        const uint2* __restrict__ ebuf, const int* __restrict__ bcur,
        uint2* __restrict__ rcb) {
    __shared__ uint2 se[REGION_CAP];   // 48 KB
    __shared__ int lhist[256];
    __shared__ int lcur[256];
    __shared__ int csc[256];
    const int b = blockIdx.x;
    const int t = threadIdx.x;
    csc[t] = (t < NBUCK) ? bcur[t] : 0;
    __syncthreads();
    for (int d = 1; d < 256; d <<= 1) {
        const int x = (t >= d) ? csc[t - d] : 0;
        __syncthreads();
        csc[t] += x;
        __syncthreads();
    }
    const int dbase = (b == 0) ? 0 : csc[b - 1];
    const int n = bcur[b];

    const uint2* src = ebuf + (size_t)b * REGION_CAP;
    for (int i = t; i < n; i += 256) se[i] = src[i];
    lhist[t] = 0;
    __syncthreads();
    for (int i = t; i < n; i += 256)
        atomicAdd(&lhist[(se[i].x >> 16) & 255u], 1);
    __syncthreads();
    int v = lhist[t];
    int sv = v;
    lcur[t] = v;
    __syncthreads();
    for (int d = 1; d < 256; d <<= 1) {
        const int x = (t >= d) ? lcur[t - d] : 0;
        __syncthreads();
        lcur[t] += x;
        __syncthreads();
        sv = lcur[t];
    }
    __syncthreads();
    lcur[t] = sv - v;  // exclusive
    __syncthreads();
    for (int i = t; i < n; i += 256) {
        const uint2 e = se[i];
        const int dst = atomicAdd(&lcur[(e.x >> 16) & 255u], 1);
        rcb[dbase + dst] = e;
    }
}

// ---------------- edge-pair gather-aggregate: 1 load instr / edge ----------------------------
// Wave processes 64 edges as 32 PAIRS: lanes 0-31 fetch e0's 256B row as uint2 (4 ch/lane),
// lanes 32-63 fetch e1's -> one dwordx2 instr moves 512B covering two edges (2x work per
// vmcnt slot). Half-wave accumulators (even/odd edges, same channels) combined at segment
// flushes via shfl_xor(32). Mid-pair col change handled with exec-masked FMA.
__global__ __launch_bounds__(256) void aggregate_kernel(
        const unsigned int* __restrict__ hhf, const uint2* __restrict__ rcb,
        const unsigned int* __restrict__ tabh, unsigned int* __restrict__ aggh) {
    // bijective XCD-chunked swizzle (NAGG=3125=8*390+5)
    const int bid = blockIdx.x;
    const int xcd = bid & 7, ix = bid >> 3;
    const int qq = NAGG >> 3, rr = NAGG & 7;
    const int blk = (xcd < rr ? xcd * (qq + 1) : rr * (qq + 1) + (xcd - rr) * qq) + ix;
    const int t = threadIdx.x;
    const int lane = t & 63;
    const int wv = __builtin_amdgcn_readfirstlane(t >> 6);
    const size_t ebase = (size_t)(blk * 4 + wv) * WEDGES;
    const int lidx = lane & 31;
    const bool lo = lane < 32;

    const uint2* hh2 = (const uint2*)hhf;
    const uint2* tb2 = (const uint2*)tabh;
    const __half2 hzero = __floats2half2_rn(0.0f, 0.0f);

    uint2 huA[4], huB[4], huC[4];
    uint2 tvA[4], tvB[4], tvC[4];
    int c0A[4], c1A[4], c0B[4], c1B[4], c0C[4], c1C[4];
    __half2 acc2a = hzero, acc2b = hzero;
    float2 accfA = make_float2(0.0f, 0.0f);
    float2 accfB = make_float2(0.0f, 0.0f);
    int sCur;
    bool first = true;

#define FLUSHSEG()                                                            \
    {                                                                         \
        {                                                                     \
            const float2 pa = __half22float2(acc2a);                          \
            const float2 pb = __half22float2(acc2b);                          \
            accfA.x += pa.x; accfA.y += pa.y;                                 \
            accfB.x += pb.x; accfB.y += pb.y;                                 \
            acc2a = hzero; acc2b = hzero;                                     \
        }                                                                     \
        const float cax = accfA.x + __shfl_xor(accfA.x, 32);                  \
        const float cay = accfA.y + __shfl_xor(accfA.y, 32);                  \
        const float cbx = accfB.x + __shfl_xor(accfB.x, 32);                  \
        const float cby = accfB.y + __shfl_xor(accfB.y, 32);                  \
        if (lo) {                                                             \
            unsigned int* dst = &aggh[(size_t)sCur * 64 + 2 * lidx];          \
            const unsigned int va = h22u(__floats2half2_rn(cax, cay));        \
            const unsigned int vb = h22u(__floats2half2_rn(cbx, cby));        \
            if (first) {                                                      \
                atomic_pk_add_h2(dst, va);                                    \
                atomic_pk_add_h2(dst + 1, vb);                                \
            } else {                                                          \
                dst[0] = va;                                                  \
                dst[1] = vb;                                                  \
            }                                                                 \
        }                                                                     \
        first = false;                                                        \
        accfA = make_float2(0.0f, 0.0f);                                      \
        accfB = make_float2(0.0f, 0.0f);                                      \
    }

#define LOADG(g, HU, TV, C0, C1)                                              \
    {                                                                         \
        _Pragma("unroll")                                                     \
        for (int u = 0; u < 4; ++u) {                                         \
            const uint4 mm = *(const uint4*)&rcb[ebase + ((g) * 4 + u) * 2];  \
            const unsigned int r0 = __builtin_amdgcn_readfirstlane(mm.x);     \
            const int b0 = __builtin_amdgcn_readfirstlane((int)mm.y);         \
            const unsigned int r1 = __builtin_amdgcn_readfirstlane(mm.z);     \
            const int b1 = __builtin_amdgcn_readfirstlane((int)mm.w);         \
            C0[u] = (int)(r0 >> 16);                                          \
            C1[u] = (int)(r1 >> 16);                                          \
            const int srow = lo ? (int)(r0 & 0xffffu) : (int)(r1 & 0xffffu);  \
            const int sbin = lo ? b0 : b1;                                    \
            HU[u] = hh2[(size_t)srow * 32 + lidx];                            \
            TV[u] = tb2[(size_t)sbin * 32 + lidx];                            \
        }                                                                     \
    }

#define COMPUTEG(HU, TV, C0, C1)                                              \
    {                                                                         \
        _Pragma("unroll")                                                     \
        for (int u = 0; u < 4; ++u) {                                         \
            const int c0 = C0[u], c1 = C1[u];                                 \
            if (c0 != sCur) { FLUSHSEG(); sCur = c0; }                        \
            const bool same = (c0 == c1);                                     \
            if (same || lo) {                                                 \
                acc2a = __hfma2(u2h2(HU[u].x), u2h2(TV[u].x), acc2a);         \
                acc2b = __hfma2(u2h2(HU[u].y), u2h2(TV[u].y), acc2b);         \
            }                                                                 \
            if (!same) {                                                      \
                FLUSHSEG();                                                   \
                sCur = c1;                                                    \
                if (!lo) {                                                    \
                    acc2a = __hfma2(u2h2(HU[u].x), u2h2(TV[u].x), acc2a);     \
                    acc2b = __hfma2(u2h2(HU[u].y), u2h2(TV[u].y), acc2b);     \
                }                                                             \
            }                                                                 \
        }                                                                     \
        {                                                                     \
            const float2 pa = __half22float2(acc2a);                          \
            const float2 pb = __half22float2(acc2b);                          \
            accfA.x += pa.x; accfA.y += pa.y;                                 \
            accfB.x += pb.x; accfB.y += pb.y;                                 \
            acc2a = hzero; acc2b = hzero;                                     \
        }                                                                     \
    }

    LOADG(0, huA, tvA, c0A, c1A);
    LOADG(1, huB, tvB, c0B, c1B);
    LOADG(2, huC, tvC, c0C, c1C);
    sCur = c0A[0];
    COMPUTEG(huA, tvA, c0A, c1A);
    LOADG(3, huA, tvA, c0A, c1A);
    COMPUTEG(huB, tvB, c0B, c1B);
    LOADG(4, huB, tvB, c0B, c1B);
    COMPUTEG(huC, tvC, c0C, c1C);
    LOADG(5, huC, tvC, c0C, c1C);
    COMPUTEG(huA, tvA, c0A, c1A);
    LOADG(6, huA, tvA, c0A, c1A);
    COMPUTEG(huB, tvB, c0B, c1B);
    LOADG(7, huB, tvB, c0B, c1B);
    COMPUTEG(huC, tvC, c0C, c1C);
    COMPUTEG(huA, tvA, c0A, c1A);
    COMPUTEG(huB, tvB, c0B, c1B);

    // final flush: may continue into next chunk -> force atomic
    first = true;
    FLUSHSEG();
#undef LOADG
#undef COMPUTEG
#undef FLUSHSEG
}

// ---------------- node via MFMA: h' = g*lrelu((h+agg)@Wn + bn)/sqrt(1+eps)+be --------------
template <int POOL, int ZERO>
__global__ __launch_bounds__(256) void node_kernel(
        unsigned int* __restrict__ hhf, unsigned int* __restrict__ aggh,
        const uint4* __restrict__ Wnb, const float* __restrict__ bn,
        const float* __restrict__ g, const float* __restrict__ be,
        const int* __restrict__ batch, float* __restrict__ out) {
    __shared__ unsigned short sA[32 * 136];   // 8704 B
    const int node0 = blockIdx.x * 32;
    const int t = threadIdx.x;
    const uint4* hh4 = (const uint4*)hhf;
    uint4* ag4 = (uint4*)aggh;
    for (int i = t; i < 32 * 16; i += 256) {
        const int n = i >> 4;
        const int pp = i & 15;
        const int node = node0 + n;
        uint4 hv, av;
        if (node < N_NODES) {
            hv = hh4[(size_t)node * 16 + pp];
            av = ag4[(size_t)node * 16 + pp];
            if (ZERO) ag4[(size_t)node * 16 + pp] = make_uint4(0u, 0u, 0u, 0u);
        } else {
            hv = make_uint4(0u, 0u, 0u, 0u);
            av = hv;
        }
        uint4 sv;
        sv.x = h22u(__hadd2(u2h2(hv.x), u2h2(av.x)));
        sv.y = h22u(__hadd2(u2h2(hv.y), u2h2(av.y)));
        sv.z = h22u(__hadd2(u2h2(hv.z), u2h2(av.z)));
        sv.w = h22u(__hadd2(u2h2(hv.w), u2h2(av.w)));
        *(uint4*)&sA[n * 136 + 8 * pp] = sv;
    }
    __syncthreads();
    const int lane = t & 63;
    const int wv = t >> 6;
    const int q = lane >> 4;
    const int r = lane & 15;
    const int ct0 = 2 * wv, ct1 = 2 * wv + 1;
    const int c0 = ct0 * 16 + r, c1 = ct1 * 16 + r;
    const float bn0 = bn[c0], bn1 = bn[c1];
    f32x4_t acc00 = {bn0, bn0, bn0, bn0};
    f32x4_t acc01 = {bn1, bn1, bn1, bn1};
    f32x4_t acc10 = {bn0, bn0, bn0, bn0};
    f32x4_t acc11 = {bn1, bn1, bn1, bn1};
#pragma unroll
    for (int kc = 0; kc < 4; ++kc) {
        const half8_t a0 = __builtin_bit_cast(half8_t,
            *(const uint4*)&sA[(size_t)r * 136 + kc * 32 + 8 * q]);
        const half8_t a1 = __builtin_bit_cast(half8_t,
            *(const uint4*)&sA[(size_t)(16 + r) * 136 + kc * 32 + 8 * q]);
        const half8_t b0 = __builtin_bit_cast(half8_t, Wnb[(kc * 8 + ct0) * 64 + lane]);
        const half8_t b1 = __builtin_bit_cast(half8_t, Wnb[(kc * 8 + ct1) * 64 + lane]);
        acc00 = __builtin_amdgcn_mfma_f32_16x16x32_f16(a0, b0, acc00, 0, 0, 0);
        acc01 = __builtin_amdgcn_mfma_f32_16x16x32_f16(a0, b1, acc01, 0, 0, 0);
        acc10 = __builtin_amdgcn_mfma_f32_16x16x32_f16(a1, b0, acc10, 0, 0, 0);
        acc11 = __builtin_amdgcn_mfma_f32_16x16x32_f16(a1, b1, acc11, 0, 0, 0);
    }
    const float inv = 0.9999950000374997f;  // 1/sqrt(1+1e-5)
    const float gv0 = g[c0] * inv, gv1 = g[c1] * inv;
    const float be0 = be[c0], be1 = be[c1];
    if (POOL == 0) {
        unsigned short* hp = (unsigned short*)hhf;
#pragma unroll
        for (int rt = 0; rt < 2; ++rt) {
            const f32x4_t aA = rt ? acc10 : acc00;
            const f32x4_t aB = rt ? acc11 : acc01;
#pragma unroll
            for (int i = 0; i < 4; ++i) {
                const int node = node0 + rt * 16 + 4 * q + i;
                if (node < N_NODES) {
                    float v0 = aA[i]; v0 = v0 > 0.0f ? v0 : LRELU_SLOPE * v0;
                    float v1 = aB[i]; v1 = v1 > 0.0f ? v1 : LRELU_SLOPE * v1;
                    hp[(size_t)node * C_H + c0] =
                        __builtin_bit_cast(unsigned short, (_Float16)fmaf(gv0, v0, be0));
                    hp[(size_t)node * C_H + c1] =
                        __builtin_bit_cast(unsigned short, (_Float16)fmaf(gv1, v1, be1));
                }
            }
        }
    } else {
        // fused global_add_pool (batch sorted; this lane's nodes visited ascending)
        float pacc0 = 0.0f, pacc1 = 0.0f;
        int curb = -1;
#pragma unroll
        for (int rt = 0; rt < 2; ++rt) {
            const f32x4_t aA = rt ? acc10 : acc00;
            const f32x4_t aB = rt ? acc11 : acc01;
#pragma unroll
            for (int i = 0; i < 4; ++i) {
                const int node = node0 + rt * 16 + 4 * q + i;
                if (node < N_NODES) {
                    float v0 = aA[i]; v0 = v0 > 0.0f ? v0 : LRELU_SLOPE * v0;
                    float v1 = aB[i]; v1 = v1 > 0.0f ? v1 : LRELU_SLOPE * v1;
                    const float o0 = fmaf(gv0, v0, be0);
                    const float o1 = fmaf(gv1, v1, be1);
                    const int bb = batch[node];
                    if (bb != curb) {
                        if (curb >= 0) {
                            atomicAdd(&out[curb * C_H + c0], pacc0);
                            atomicAdd(&out[curb * C_H + c1], pacc1);
                        }
                        pacc0 = 0.0f; pacc1 = 0.0f;
                        curb = bb;
                    }
                    pacc0 += o0;
                    pacc1 += o1;
                }
            }
        }
        if (curb >= 0) {
            atomicAdd(&out[curb * C_H + c0], pacc0);
            atomicAdd(&out[curb * C_H + c1], pacc1);
        }
    }
}

extern "C" void kernel_launch(void* const* d_in, const int* in_sizes, int n_in,
                              void* d_out, int out_size, void* d_ws, size_t ws_size,
                              hipStream_t stream) {
    const float* x     = (const float*)d_in[0];
    const float* pos   = (const float*)d_in[1];
    const int*   eidx  = (const int*)d_in[2];
    const int*   batch = (const int*)d_in[3];
    const float* W_lin = (const float*)d_in[4];
    const float* b_lin = (const float*)d_in[5];

    unsigned int* aggh = (unsigned int*)d_ws;                          // 12.8 MB (half2)
    unsigned int* hhf  = aggh + (size_t)N_NODES * 64;                  // 12.8 MB
    unsigned int* Wnh  = hhf + (size_t)N_NODES * 64;                   // 3 * 32 KB (B frags)
    unsigned int* tabh = Wnh + 3 * C_H * 64;                           // 3 * 2 MB
    int* bcur = (int*)(tabh + 3 * (size_t)TAB_BINS * 64);              // 196
    uintptr_t p = (uintptr_t)(bcur + NBUCK);
    p = (p + 15) & ~(uintptr_t)15;
    uint2* ebuf = (uint2*)p;                                           // 9.6 MB
    uint2* rcb  = ebuf + (size_t)NBUCK * REGION_CAP;                   // 6.4 MB

    const int* row = eidx;
    const int* col = eidx + N_EDGES;

    // setup: 3 tables + 3 Wn frag-swizzles + agg zero + lin0 + out zero + bcur zero
    hipLaunchKernelGGL(setup_kernel, dim3(SETUP_GRID), dim3(256), 0, stream,
                       (const float*)d_in[6],  (const float*)d_in[7],
                       (const float*)d_in[12], (const float*)d_in[13],
                       (const float*)d_in[18], (const float*)d_in[19],
                       (const float*)d_in[8],  (const float*)d_in[14],
                       (const float*)d_in[20],
                       x, W_lin, b_lin,
                       tabh, Wnh, (uint4*)aggh, hhf, (uint4*)d_out, bcur);

    // bucketed CSR build
    hipLaunchKernelGGL(bscatter_kernel,
                       dim3((N_EDGES + SCAT_BLK_EDGES - 1) / SCAT_BLK_EDGES), dim3(256),
                       0, stream, row, col, pos, bcur, ebuf);
    hipLaunchKernelGGL(bsort_kernel, dim3(NBUCK), dim3(256), 0, stream,
                       ebuf, bcur, rcb);

    for (int l = 0; l < 3; ++l) {
        const float* bn = (const float*)d_in[6 + l * 6 + 3];
        const float* g  = (const float*)d_in[6 + l * 6 + 4];
        const float* be = (const float*)d_in[6 + l * 6 + 5];
        unsigned int* tab_l = tabh + (size_t)l * TAB_BINS * 64;
        const uint4* Wnb_l = (const uint4*)Wnh + (size_t)l * 2048;

        hipLaunchKernelGGL(aggregate_kernel, dim3(NAGG), dim3(256), 0, stream,
                           hhf, rcb, tab_l, aggh);
        if (l < 2) {
            hipLaunchKernelGGL(HIP_KERNEL_NAME(node_kernel<0, 1>),
                               dim3((N_NODES + 31) / 32), dim3(256), 0, stream,
                               hhf, aggh, Wnb_l, bn, g, be, batch, (float*)d_out);
        } else {
            hipLaunchKernelGGL(HIP_KERNEL_NAME(node_kernel<1, 0>),
                               dim3((N_NODES + 31) / 32), dim3(256), 0, stream,
                               hhf, aggh, Wnb_l, bn, g, be, batch, (float*)d_out);
        }
    }
}

// Round 19
// 195.704 us; speedup vs baseline: 1.1307x; 1.1307x over previous
//
#include <hip/hip_runtime.h>
#include <hip/hip_fp16.h>
#include <math.h>

#define N_NODES 50000
#define N_EDGES 800000
#define NUM_GRAPHS 256
#define C_IN 64
#define C_H 128
#define D_COUNT 9
#define LRELU_SLOPE 0.01f
#define TAB_BINS 4096
#define TAB_SCALE 512.0f                   // bins per unit distance, covers d in [0,8)
#define WEDGES 64                          // edges per wave
#define NCHUNK (N_EDGES / WEDGES)          // 12500 wave-chunks
#define NAGG (NCHUNK / 4)                  // 3125 aggregate blocks
#define NBUCK ((N_NODES + 255) / 256)      // 196 coarse buckets (col>>8)
#define REGION_CAP 6144
#define SCAT_BLK_EDGES 2048
// setup_kernel grid partition
#define TBLK (TAB_BINS * 64 / 256)         // 1024 blocks per radial table
#define WNBLK 8                            // 8 blocks per Wn fragment-swizzle (2048 uint4)
#define ZBLK 1024                          // agg zero (grid-stride)
#define LIN0BLK ((N_NODES + 31) / 32)      // 1563 lin0 tiles
#define OUTZBLK 32                         // d_out zero
#define OFF1 (3 * TBLK)
#define OFF2 (OFF1 + 3 * WNBLK)
#define OFF3 (OFF2 + ZBLK)
#define OFF4 (OFF3 + LIN0BLK)
#define OFF5 (OFF4 + OUTZBLK)
#define SETUP_GRID (OFF5 + 1)              // +1 block: bcur zero

typedef _Float16 half8_t __attribute__((ext_vector_type(8)));
typedef float f32x4_t __attribute__((ext_vector_type(4)));

__device__ __forceinline__ float fast_rcp(float x) { return __builtin_amdgcn_rcpf(x); }
__device__ __forceinline__ __half2 u2h2(unsigned int u) { return __builtin_bit_cast(__half2, u); }
__device__ __forceinline__ unsigned int h22u(__half2 h) { return __builtin_bit_cast(unsigned int, h); }

__device__ __forceinline__ void atomic_pk_add_h2(unsigned int* addr, unsigned int val) {
    asm volatile("global_atomic_pk_add_f16 %0, %1, off"
                 :: "v"(addr), "v"(val) : "memory");
}

// ---------------- setup: tables + Wn frag-swizzle + agg zero + lin0 + out zero + bcur ------
__global__ __launch_bounds__(256) void setup_kernel(
        const float* __restrict__ Wc1, const float* __restrict__ bc1,
        const float* __restrict__ Wc2, const float* __restrict__ bc2,
        const float* __restrict__ Wc3, const float* __restrict__ bc3,
        const float* __restrict__ Wn1, const float* __restrict__ Wn2,
        const float* __restrict__ Wn3,
        const float* __restrict__ x, const float* __restrict__ Wl,
        const float* __restrict__ bl,
        unsigned int* __restrict__ tabh, unsigned int* __restrict__ Wnh,
        uint4* __restrict__ aggz, unsigned int* __restrict__ hhf,
        uint4* __restrict__ outz, int* __restrict__ bcur) {
    __shared__ float xs[32][C_IN];
    const int b = blockIdx.x;
    const int t = threadIdx.x;
    if (b < OFF1) {
        const int l = b / TBLK;
        const float* Wc = (l == 0) ? Wc1 : (l == 1) ? Wc2 : Wc3;
        const float* bc = (l == 0) ? bc1 : (l == 1) ? bc2 : bc3;
        const int idx = (b - l * TBLK) * 256 + t;
        const int lane = idx & 63;
        const int bin = idx >> 6;
        const float d = ((float)bin + 0.5f) * (1.0f / TAB_SCALE);
        float v[2];
#pragma unroll
        for (int p = 0; p < 2; ++p) {
            const int c = 2 * lane + p;
            float a = bc[c];
#pragma unroll
            for (int k = 0; k < D_COUNT; ++k) {
                const float u = (d - 0.75f * (float)k) * 1.5f;  // mu=0.75k, 1/sigma=1.5
                a = fmaf(__expf(-u * u), Wc[k * C_H + c], a);
            }
            v[p] = a * fast_rcp(1.0f + __expf(-a));
        }
        tabh[(size_t)l * TAB_BINS * 64 + idx] = h22u(__floats2half2_rn(v[0], v[1]));
    } else if (b < OFF2) {
        // Wn -> MFMA B-fragment order: Wnb[l][(kc*8+ct)*64 + lane] = 8 halves
        const int bb = b - OFF1;
        const int l = bb / WNBLK;
        const float* Wn = (l == 0) ? Wn1 : (l == 1) ? Wn2 : Wn3;
        const int idx = (bb - l * WNBLK) * 256 + t;   // 0..2047
        const int lane = idx & 63;
        const int tile = idx >> 6;                    // 0..31
        const int kc = tile >> 3, ct = tile & 7;
        const int q = lane >> 4, r = lane & 15;
        half8_t v;
#pragma unroll
        for (int j = 0; j < 8; ++j)
            v[j] = (_Float16)Wn[(size_t)(kc * 32 + 8 * q + j) * C_H + ct * 16 + r];
        ((uint4*)Wnh)[(size_t)l * 2048 + idx] = __builtin_bit_cast(uint4, v);
    } else if (b < OFF3) {
        const int n16 = N_NODES * 16;
        const int stride = ZBLK * 256;
        for (int i = (b - OFF2) * 256 + t; i < n16; i += stride)
            aggz[i] = make_uint4(0u, 0u, 0u, 0u);
    } else if (b < OFF4) {
        // lin0: hhf = half2(silu(x @ Wl + bl))
        const int node0 = (b - OFF3) * 32;
        for (int i = t * 4; i < 32 * C_IN; i += 256 * 4) {
            const int n = i >> 6;
            const int c = i & 63;
            if (node0 + n < N_NODES)
                *(float4*)&xs[n][c] = *(const float4*)&x[(size_t)(node0 + n) * C_IN + c];
        }
        __syncthreads();
        const int wv = t >> 6;
        const int lane = t & 63;
        const int nb = wv * 8;
        const float2 b2 = *(const float2*)&bl[2 * lane];
        float2 acc[8];
#pragma unroll
        for (int n = 0; n < 8; ++n) acc[n] = b2;
        for (int k = 0; k < C_IN; k += 4) {
            const float2 w0 = *(const float2*)&Wl[(size_t)(k + 0) * C_H + 2 * lane];
            const float2 w1 = *(const float2*)&Wl[(size_t)(k + 1) * C_H + 2 * lane];
            const float2 w2 = *(const float2*)&Wl[(size_t)(k + 2) * C_H + 2 * lane];
            const float2 w3 = *(const float2*)&Wl[(size_t)(k + 3) * C_H + 2 * lane];
#pragma unroll
            for (int n = 0; n < 8; ++n) {
                const float4 sv = *(const float4*)&xs[nb + n][k];
                acc[n].x = fmaf(sv.x, w0.x, acc[n].x); acc[n].y = fmaf(sv.x, w0.y, acc[n].y);
                acc[n].x = fmaf(sv.y, w1.x, acc[n].x); acc[n].y = fmaf(sv.y, w1.y, acc[n].y);
                acc[n].x = fmaf(sv.z, w2.x, acc[n].x); acc[n].y = fmaf(sv.z, w2.y, acc[n].y);
                acc[n].x = fmaf(sv.w, w3.x, acc[n].x); acc[n].y = fmaf(sv.w, w3.y, acc[n].y);
            }
        }
#pragma unroll
        for (int n = 0; n < 8; ++n) {
            const int node = node0 + nb + n;
            if (node < N_NODES) {
                const float ax = acc[n].x, ay = acc[n].y;
                const float sx = ax * fast_rcp(1.0f + __expf(-ax));
                const float sy = ay * fast_rcp(1.0f + __expf(-ay));
                hhf[(size_t)node * 64 + lane] = h22u(__floats2half2_rn(sx, sy));
            }
        }
    } else if (b < OFF5) {
        const int n16 = NUM_GRAPHS * C_H / 4;
        const int stride = OUTZBLK * 256;
        for (int i = (b - OFF4) * 256 + t; i < n16; i += stride)
            outz[i] = make_uint4(0u, 0u, 0u, 0u);
    } else {
        if (t < NBUCK) bcur[t] = 0;
    }
}

// ---------------- bucketed CSR build ---------------------------------------------------------
__global__ __launch_bounds__(256) void bscatter_kernel(
        const int* __restrict__ row, const int* __restrict__ col,
        const float* __restrict__ pos, int* __restrict__ bcur, uint2* __restrict__ ebuf) {
    __shared__ int lhist[NBUCK];
    __shared__ int lcur[NBUCK];
    const int t = threadIdx.x;
    const int e0 = blockIdx.x * SCAT_BLK_EDGES;
    for (int i = t; i < NBUCK; i += 256) lhist[i] = 0;
    __syncthreads();

    int myb[8];
    uint2 myrec[8];
#pragma unroll
    for (int s = 0; s < 8; ++s) {
        const int e = e0 + s * 256 + t;
        if (e < N_EDGES) {
            const int r = row[e];
            const int c = col[e];
            const float dx = pos[r * 3 + 0] - pos[c * 3 + 0];
            const float dy = pos[r * 3 + 1] - pos[c * 3 + 1];
            const float dz = pos[r * 3 + 2] - pos[c * 3 + 2];
            const float d = sqrtf(dx * dx + dy * dy + dz * dz);
            int bin = (int)(d * TAB_SCALE);
            bin = bin < TAB_BINS - 1 ? bin : TAB_BINS - 1;
            myb[s] = c >> 8;
            myrec[s] = make_uint2((unsigned int)r | ((unsigned int)c << 16),
                                  (unsigned int)bin);
            atomicAdd(&lhist[myb[s]], 1);
        } else {
            myb[s] = -1;
        }
    }
    __syncthreads();
    for (int i = t; i < NBUCK; i += 256)
        lcur[i] = (lhist[i] > 0) ? atomicAdd(&bcur[i], lhist[i]) : 0;
    __syncthreads();
#pragma unroll
    for (int s = 0; s < 8; ++s) {
        if (myb[s] >= 0) {
            const int p = atomicAdd(&lcur[myb[s]], 1);
            ebuf[(size_t)myb[s] * REGION_CAP + p] = myrec[s];
        }
    }
}

__global__ __launch_bounds__(256) void bsort_kernel(
        const uint2* __restrict__ ebuf, const int* __restrict__ bcur,
        uint2* __restrict__ rcb) {
    __shared__ uint2 se[REGION_CAP];   // 48 KB
    __shared__ int lhist[256];
    __shared__ int lcur[256];
    __shared__ int csc[256];
    const int b = blockIdx.x;
    const int t = threadIdx.x;
    csc[t] = (t < NBUCK) ? bcur[t] : 0;
    __syncthreads();
    for (int d = 1; d < 256; d <<= 1) {
        const int x = (t >= d) ? csc[t - d] : 0;
        __syncthreads();
        csc[t] += x;
        __syncthreads();
    }
    const int dbase = (b == 0) ? 0 : csc[b - 1];
    const int n = bcur[b];

    const uint2* src = ebuf + (size_t)b * REGION_CAP;
    for (int i = t; i < n; i += 256) se[i] = src[i];
    lhist[t] = 0;
    __syncthreads();
    for (int i = t; i < n; i += 256)
        atomicAdd(&lhist[(se[i].x >> 16) & 255u], 1);
    __syncthreads();
    int v = lhist[t];
    int sv = v;
    lcur[t] = v;
    __syncthreads();
    for (int d = 1; d < 256; d <<= 1) {
        const int x = (t >= d) ? lcur[t - d] : 0;
        __syncthreads();
        lcur[t] += x;
        __syncthreads();
        sv = lcur[t];
    }
    __syncthreads();
    lcur[t] = sv - v;  // exclusive
    __syncthreads();
    for (int i = t; i < n; i += 256) {
        const uint2 e = se[i];
        const int dst = atomicAdd(&lcur[(e.x >> 16) & 255u], 1);
        rcb[dbase + dst] = e;
    }
}

// ---------------- edge-parallel gather-aggregate (scalar meta, depth-4, XCD swizzle) --------
// Interior-segment flushes use NONTEMPORAL stores: agg lines are write-once/read-later,
// keeping them out of L2 preserves capacity for the random h-gather + table.
__global__ __launch_bounds__(256) void aggregate_kernel(
        const unsigned int* __restrict__ hhf, const uint2* __restrict__ rcb,
        const unsigned int* __restrict__ tabh, unsigned int* __restrict__ aggh) {
    const int bid = blockIdx.x;
    const int xcd = bid & 7, ix = bid >> 3;
    const int qq = NAGG >> 3, rr = NAGG & 7;   // 390, 5
    const int blk = (xcd < rr ? xcd * (qq + 1) : rr * (qq + 1) + (xcd - rr) * qq) + ix;
    const int t = threadIdx.x;
    const int lane = t & 63;
    const int wv = __builtin_amdgcn_readfirstlane(t >> 6);
    const size_t base = (size_t)(blk * 4 + wv) * WEDGES;

    const __half2 hzero = __floats2half2_rn(0.0f, 0.0f);

    unsigned int huA[8], huB[8], huC[8], huD[8];
    unsigned int tvA[8], tvB[8], tvC[8], tvD[8];
    int colA[8], colB[8], colC[8], colD[8];
    __half2 acc2 = hzero;
    float2 accf = make_float2(0.0f, 0.0f);
    int sCur;
    bool first = true;

#define LOADG(g, HU, TV, CO)                                                  \
    {                                                                         \
        _Pragma("unroll")                                                     \
        for (int u = 0; u < 8; ++u) {                                         \
            const uint2 m = rcb[base + (g) * 8 + u];                          \
            const unsigned int rcu = __builtin_amdgcn_readfirstlane(m.x);     \
            const int sBin = __builtin_amdgcn_readfirstlane((int)m.y);        \
            const int sRow = (int)(rcu & 0xffffu);                            \
            CO[u] = (int)(rcu >> 16);                                         \
            HU[u] = hhf[(size_t)sRow * 64 + lane];                            \
            TV[u] = tabh[(size_t)sBin * 64 + lane];                           \
        }                                                                     \
    }

#define COMPUTEG(HU, TV, CO)                                                  \
    {                                                                         \
        _Pragma("unroll")                                                     \
        for (int u = 0; u < 8; ++u) {                                         \
            if (CO[u] != sCur) {                                              \
                const float2 pf = __half22float2(acc2);                       \
                accf.x += pf.x; accf.y += pf.y; acc2 = hzero;                 \
                unsigned int* dst = &aggh[(size_t)sCur * 64 + lane];          \
                const unsigned int hv = h22u(__floats2half2_rn(accf.x, accf.y)); \
                if (first) {                                                  \
                    atomic_pk_add_h2(dst, hv);                                \
                    first = false;                                            \
                } else {                                                      \
                    __builtin_nontemporal_store(hv, dst);                     \
                }                                                             \
                accf.x = 0.0f; accf.y = 0.0f;                                 \
                sCur = CO[u];                                                 \
            }                                                                 \
            acc2 = __hfma2(u2h2(HU[u]), u2h2(TV[u]), acc2);                   \
        }                                                                     \
        const float2 pg = __half22float2(acc2);                               \
        accf.x += pg.x; accf.y += pg.y; acc2 = hzero;                         \
    }

    LOADG(0, huA, tvA, colA);
    LOADG(1, huB, tvB, colB);
    LOADG(2, huC, tvC, colC);
    LOADG(3, huD, tvD, colD);
    sCur = colA[0];
    COMPUTEG(huA, tvA, colA);
    LOADG(4, huA, tvA, colA);
    COMPUTEG(huB, tvB, colB);
    LOADG(5, huB, tvB, colB);
    COMPUTEG(huC, tvC, colC);
    LOADG(6, huC, tvC, colC);
    COMPUTEG(huD, tvD, colD);
    LOADG(7, huD, tvD, colD);
    COMPUTEG(huA, tvA, colA);
    COMPUTEG(huB, tvB, colB);
    COMPUTEG(huC, tvC, colC);
    COMPUTEG(huD, tvD, colD);

    {
        unsigned int* dst = &aggh[(size_t)sCur * 64 + lane];
        atomic_pk_add_h2(dst, h22u(__floats2half2_rn(accf.x, accf.y)));
    }
#undef LOADG
#undef COMPUTEG
}

// ---------------- node via MFMA: h' = g*lrelu((h+agg)@Wn + bn)/sqrt(1+eps)+be --------------
template <int POOL, int ZERO>
__global__ __launch_bounds__(256) void node_kernel(
        unsigned int* __restrict__ hhf, unsigned int* __restrict__ aggh,
        const uint4* __restrict__ Wnb, const float* __restrict__ bn,
        const float* __restrict__ g, const float* __restrict__ be,
        const int* __restrict__ batch, float* __restrict__ out) {
    __shared__ unsigned short sA[32 * 136];   // 8704 B
    const int node0 = blockIdx.x * 32;
    const int t = threadIdx.x;
    const uint4* hh4 = (const uint4*)hhf;
    uint4* ag4 = (uint4*)aggh;
    for (int i = t; i < 32 * 16; i += 256) {
        const int n = i >> 4;
        const int pp = i & 15;
        const int node = node0 + n;
        uint4 hv, av;
        if (node < N_NODES) {
            hv = hh4[(size_t)node * 16 + pp];
            av = ag4[(size_t)node * 16 + pp];
            if (ZERO) ag4[(size_t)node * 16 + pp] = make_uint4(0u, 0u, 0u, 0u);
        } else {
            hv = make_uint4(0u, 0u, 0u, 0u);
            av = hv;
        }
        uint4 sv;
        sv.x = h22u(__hadd2(u2h2(hv.x), u2h2(av.x)));
        sv.y = h22u(__hadd2(u2h2(hv.y), u2h2(av.y)));
        sv.z = h22u(__hadd2(u2h2(hv.z), u2h2(av.z)));
        sv.w = h22u(__hadd2(u2h2(hv.w), u2h2(av.w)));
        *(uint4*)&sA[n * 136 + 8 * pp] = sv;
    }
    __syncthreads();
    const int lane = t & 63;
    const int wv = t >> 6;
    const int q = lane >> 4;
    const int r = lane & 15;
    const int ct0 = 2 * wv, ct1 = 2 * wv + 1;
    const int c0 = ct0 * 16 + r, c1 = ct1 * 16 + r;
    const float bn0 = bn[c0], bn1 = bn[c1];
    f32x4_t acc00 = {bn0, bn0, bn0, bn0};
    f32x4_t acc01 = {bn1, bn1, bn1, bn1};
    f32x4_t acc10 = {bn0, bn0, bn0, bn0};
    f32x4_t acc11 = {bn1, bn1, bn1, bn1};
#pragma unroll
    for (int kc = 0; kc < 4; ++kc) {
        const half8_t a0 = __builtin_bit_cast(half8_t,
            *(const uint4*)&sA[(size_t)r * 136 + kc * 32 + 8 * q]);
        const half8_t a1 = __builtin_bit_cast(half8_t,
            *(const uint4*)&sA[(size_t)(16 + r) * 136 + kc * 32 + 8 * q]);
        const half8_t b0 = __builtin_bit_cast(half8_t, Wnb[(kc * 8 + ct0) * 64 + lane]);
        const half8_t b1 = __builtin_bit_cast(half8_t, Wnb[(kc * 8 + ct1) * 64 + lane]);
        acc00 = __builtin_amdgcn_mfma_f32_16x16x32_f16(a0, b0, acc00, 0, 0, 0);
        acc01 = __builtin_amdgcn_mfma_f32_16x16x32_f16(a0, b1, acc01, 0, 0, 0);
        acc10 = __builtin_amdgcn_mfma_f32_16x16x32_f16(a1, b0, acc10, 0, 0, 0);
        acc11 = __builtin_amdgcn_mfma_f32_16x16x32_f16(a1, b1, acc11, 0, 0, 0);
    }
    const float inv = 0.9999950000374997f;  // 1/sqrt(1+1e-5)
    const float gv0 = g[c0] * inv, gv1 = g[c1] * inv;
    const float be0 = be[c0], be1 = be[c1];
    if (POOL == 0) {
        unsigned short* hp = (unsigned short*)hhf;
#pragma unroll
        for (int rt = 0; rt < 2; ++rt) {
            const f32x4_t aA = rt ? acc10 : acc00;
            const f32x4_t aB = rt ? acc11 : acc01;
#pragma unroll
            for (int i = 0; i < 4; ++i) {
                const int node = node0 + rt * 16 + 4 * q + i;
                if (node < N_NODES) {
                    float v0 = aA[i]; v0 = v0 > 0.0f ? v0 : LRELU_SLOPE * v0;
                    float v1 = aB[i]; v1 = v1 > 0.0f ? v1 : LRELU_SLOPE * v1;
                    hp[(size_t)node * C_H + c0] =
                        __builtin_bit_cast(unsigned short, (_Float16)fmaf(gv0, v0, be0));
                    hp[(size_t)node * C_H + c1] =
                        __builtin_bit_cast(unsigned short, (_Float16)fmaf(gv1, v1, be1));
                }
            }
        }
    } else {
        // fused global_add_pool (batch sorted; this lane's nodes visited ascending)
        float pacc0 = 0.0f, pacc1 = 0.0f;
        int curb = -1;
#pragma unroll
        for (int rt = 0; rt < 2; ++rt) {
            const f32x4_t aA = rt ? acc10 : acc00;
            const f32x4_t aB = rt ? acc11 : acc01;
#pragma unroll
            for (int i = 0; i < 4; ++i) {
                const int node = node0 + rt * 16 + 4 * q + i;
                if (node < N_NODES) {
                    float v0 = aA[i]; v0 = v0 > 0.0f ? v0 : LRELU_SLOPE * v0;
                    float v1 = aB[i]; v1 = v1 > 0.0f ? v1 : LRELU_SLOPE * v1;
                    const float o0 = fmaf(gv0, v0, be0);
                    const float o1 = fmaf(gv1, v1, be1);
                    const int bb = batch[node];
                    if (bb != curb) {
                        if (curb >= 0) {
                            atomicAdd(&out[curb * C_H + c0], pacc0);
                            atomicAdd(&out[curb * C_H + c1], pacc1);
                        }
                        pacc0 = 0.0f; pacc1 = 0.0f;
                        curb = bb;
                    }
                    pacc0 += o0;
                    pacc1 += o1;
                }
            }
        }
        if (curb >= 0) {
            atomicAdd(&out[curb * C_H + c0], pacc0);
            atomicAdd(&out[curb * C_H + c1], pacc1);
        }
    }
}

extern "C" void kernel_launch(void* const* d_in, const int* in_sizes, int n_in,
                              void* d_out, int out_size, void* d_ws, size_t ws_size,
                              hipStream_t stream) {
    const float* x     = (const float*)d_in[0];
    const float* pos   = (const float*)d_in[1];
    const int*   eidx  = (const int*)d_in[2];
    const int*   batch = (const int*)d_in[3];
    const float* W_lin = (const float*)d_in[4];
    const float* b_lin = (const float*)d_in[5];

    unsigned int* aggh = (unsigned int*)d_ws;                          // 12.8 MB (half2)
    unsigned int* hhf  = aggh + (size_t)N_NODES * 64;                  // 12.8 MB
    unsigned int* Wnh  = hhf + (size_t)N_NODES * 64;                   // 3 * 32 KB (B frags)
    unsigned int* tabh = Wnh + 3 * C_H * 64;                           // 3 * 1 MB
    int* bcur = (int*)(tabh + 3 * (size_t)TAB_BINS * 64);              // 196
    uintptr_t p = (uintptr_t)(bcur + NBUCK);
    p = (p + 15) & ~(uintptr_t)15;
    uint2* ebuf = (uint2*)p;                                           // 9.6 MB
    uint2* rcb  = ebuf + (size_t)NBUCK * REGION_CAP;                   // 6.4 MB

    const int* row = eidx;
    const int* col = eidx + N_EDGES;

    // setup: 3 tables + 3 Wn frag-swizzles + agg zero + lin0 + out zero + bcur zero
    hipLaunchKernelGGL(setup_kernel, dim3(SETUP_GRID), dim3(256), 0, stream,
                       (const float*)d_in[6],  (const float*)d_in[7],
                       (const float*)d_in[12], (const float*)d_in[13],
                       (const float*)d_in[18], (const float*)d_in[19],
                       (const float*)d_in[8],  (const float*)d_in[14],
                       (const float*)d_in[20],
                       x, W_lin, b_lin,
                       tabh, Wnh, (uint4*)aggh, hhf, (uint4*)d_out, bcur);

    // bucketed CSR build
    hipLaunchKernelGGL(bscatter_kernel,
                       dim3((N_EDGES + SCAT_BLK_EDGES - 1) / SCAT_BLK_EDGES), dim3(256),
                       0, stream, row, col, pos, bcur, ebuf);
    hipLaunchKernelGGL(bsort_kernel, dim3(NBUCK), dim3(256), 0, stream,
                       ebuf, bcur, rcb);

    for (int l = 0; l < 3; ++l) {
        const float* bn = (const float*)d_in[6 + l * 6 + 3];
        const float* g  = (const float*)d_in[6 + l * 6 + 4];
        const float* be = (const float*)d_in[6 + l * 6 + 5];
        unsigned int* tab_l = tabh + (size_t)l * TAB_BINS * 64;
        const uint4* Wnb_l = (const uint4*)Wnh + (size_t)l * 2048;

        hipLaunchKernelGGL(aggregate_kernel, dim3(NAGG), dim3(256), 0, stream,
                           hhf, rcb, tab_l, aggh);
        if (l < 2) {
            hipLaunchKernelGGL(HIP_KERNEL_NAME(node_kernel<0, 1>),
                               dim3((N_NODES + 31) / 32), dim3(256), 0, stream,
                               hhf, aggh, Wnb_l, bn, g, be, batch, (float*)d_out);
        } else {
            hipLaunchKernelGGL(HIP_KERNEL_NAME(node_kernel<1, 0>),
                               dim3((N_NODES + 31) / 32), dim3(256), 0, stream,
                               hhf, aggh, Wnb_l, bn, g, be, batch, (float*)d_out);
        }
    }
}

// Round 21
// 189.365 us; speedup vs baseline: 1.1685x; 1.0335x over previous
//
#include <hip/hip_runtime.h>
#include <hip/hip_fp16.h>
#include <math.h>

#define N_NODES 50000
#define N_EDGES 800000
#define NUM_GRAPHS 256
#define C_IN 64
#define C_H 128
#define D_COUNT 9
#define LRELU_SLOPE 0.01f
#define TAB_BINS 2048
#define TAB_SCALE 256.0f                   // bins per unit distance, covers d in [0,8)
#define WEDGES 64                          // edges per wave
#define NCHUNK (N_EDGES / WEDGES)          // 12500 wave-chunks
#define NAGG (NCHUNK / 4)                  // 3125 aggregate blocks
#define NBUCK ((N_NODES + 255) / 256)      // 196 coarse buckets (col>>8)
#define REGION_CAP 6144
#define SCAT_BLK_EDGES 2048
// setup_kernel grid partition
#define TBLK (TAB_BINS * 64 / 256)         // 512 blocks per radial table
#define WNBLK 8                            // 8 blocks per Wn fragment-swizzle (2048 uint4)
#define ZBLK 1024                          // agg zero (grid-stride)
#define LIN0BLK ((N_NODES + 31) / 32)      // 1563 lin0 tiles
#define OUTZBLK 32                         // d_out zero
#define OFF1 (3 * TBLK)
#define OFF2 (OFF1 + 3 * WNBLK)
#define OFF3 (OFF2 + ZBLK)
#define OFF4 (OFF3 + LIN0BLK)
#define OFF5 (OFF4 + OUTZBLK)
#define SETUP_GRID (OFF5 + 1)              // +1 block: bcur zero

typedef _Float16 half8_t __attribute__((ext_vector_type(8)));
typedef float f32x4_t __attribute__((ext_vector_type(4)));

__device__ __forceinline__ float fast_rcp(float x) { return __builtin_amdgcn_rcpf(x); }
__device__ __forceinline__ __half2 u2h2(unsigned int u) { return __builtin_bit_cast(__half2, u); }
__device__ __forceinline__ unsigned int h22u(__half2 h) { return __builtin_bit_cast(unsigned int, h); }

__device__ __forceinline__ void atomic_pk_add_h2(unsigned int* addr, unsigned int val) {
    asm volatile("global_atomic_pk_add_f16 %0, %1, off"
                 :: "v"(addr), "v"(val) : "memory");
}

// ---------------- setup: tables + Wn frag-swizzle + agg zero + lin0 + out zero + bcur ------
__global__ __launch_bounds__(256) void setup_kernel(
        const float* __restrict__ Wc1, const float* __restrict__ bc1,
        const float* __restrict__ Wc2, const float* __restrict__ bc2,
        const float* __restrict__ Wc3, const float* __restrict__ bc3,
        const float* __restrict__ Wn1, const float* __restrict__ Wn2,
        const float* __restrict__ Wn3,
        const float* __restrict__ x, const float* __restrict__ Wl,
        const float* __restrict__ bl,
        unsigned int* __restrict__ tabh, unsigned int* __restrict__ Wnh,
        uint4* __restrict__ aggz, unsigned int* __restrict__ hhf,
        uint4* __restrict__ outz, int* __restrict__ bcur) {
    __shared__ float xs[32][C_IN];
    const int b = blockIdx.x;
    const int t = threadIdx.x;
    if (b < OFF1) {
        const int l = b / TBLK;
        const float* Wc = (l == 0) ? Wc1 : (l == 1) ? Wc2 : Wc3;
        const float* bc = (l == 0) ? bc1 : (l == 1) ? bc2 : bc3;
        const int idx = (b - l * TBLK) * 256 + t;
        const int lane = idx & 63;
        const int bin = idx >> 6;
        const float d = ((float)bin + 0.5f) * (1.0f / TAB_SCALE);
        float v[2];
#pragma unroll
        for (int p = 0; p < 2; ++p) {
            const int c = 2 * lane + p;
            float a = bc[c];
#pragma unroll
            for (int k = 0; k < D_COUNT; ++k) {
                const float u = (d - 0.75f * (float)k) * 1.5f;  // mu=0.75k, 1/sigma=1.5
                a = fmaf(__expf(-u * u), Wc[k * C_H + c], a);
            }
            v[p] = a * fast_rcp(1.0f + __expf(-a));
        }
        tabh[(size_t)l * TAB_BINS * 64 + idx] = h22u(__floats2half2_rn(v[0], v[1]));
    } else if (b < OFF2) {
        // Wn -> MFMA B-fragment order: Wnb[l][(kc*8+ct)*64 + lane] = 8 halves
        const int bb = b - OFF1;
        const int l = bb / WNBLK;
        const float* Wn = (l == 0) ? Wn1 : (l == 1) ? Wn2 : Wn3;
        const int idx = (bb - l * WNBLK) * 256 + t;   // 0..2047
        const int lane = idx & 63;
        const int tile = idx >> 6;                    // 0..31
        const int kc = tile >> 3, ct = tile & 7;
        const int q = lane >> 4, r = lane & 15;
        half8_t v;
#pragma unroll
        for (int j = 0; j < 8; ++j)
            v[j] = (_Float16)Wn[(size_t)(kc * 32 + 8 * q + j) * C_H + ct * 16 + r];
        ((uint4*)Wnh)[(size_t)l * 2048 + idx] = __builtin_bit_cast(uint4, v);
    } else if (b < OFF3) {
        const int n16 = N_NODES * 16;
        const int stride = ZBLK * 256;
        for (int i = (b - OFF2) * 256 + t; i < n16; i += stride)
            aggz[i] = make_uint4(0u, 0u, 0u, 0u);
    } else if (b < OFF4) {
        // lin0: hhf = half2(silu(x @ Wl + bl))
        const int node0 = (b - OFF3) * 32;
        for (int i = t * 4; i < 32 * C_IN; i += 256 * 4) {
            const int n = i >> 6;
            const int c = i & 63;
            if (node0 + n < N_NODES)
                *(float4*)&xs[n][c] = *(const float4*)&x[(size_t)(node0 + n) * C_IN + c];
        }
        __syncthreads();
        const int wv = t >> 6;
        const int lane = t & 63;
        const int nb = wv * 8;
        const float2 b2 = *(const float2*)&bl[2 * lane];
        float2 acc[8];
#pragma unroll
        for (int n = 0; n < 8; ++n) acc[n] = b2;
        for (int k = 0; k < C_IN; k += 4) {
            const float2 w0 = *(const float2*)&Wl[(size_t)(k + 0) * C_H + 2 * lane];
            const float2 w1 = *(const float2*)&Wl[(size_t)(k + 1) * C_H + 2 * lane];
            const float2 w2 = *(const float2*)&Wl[(size_t)(k + 2) * C_H + 2 * lane];
            const float2 w3 = *(const float2*)&Wl[(size_t)(k + 3) * C_H + 2 * lane];
#pragma unroll
            for (int n = 0; n < 8; ++n) {
                const float4 sv = *(const float4*)&xs[nb + n][k];
                acc[n].x = fmaf(sv.x, w0.x, acc[n].x); acc[n].y = fmaf(sv.x, w0.y, acc[n].y);
                acc[n].x = fmaf(sv.y, w1.x, acc[n].x); acc[n].y = fmaf(sv.y, w1.y, acc[n].y);
                acc[n].x = fmaf(sv.z, w2.x, acc[n].x); acc[n].y = fmaf(sv.z, w2.y, acc[n].y);
                acc[n].x = fmaf(sv.w, w3.x, acc[n].x); acc[n].y = fmaf(sv.w, w3.y, acc[n].y);
            }
        }
#pragma unroll
        for (int n = 0; n < 8; ++n) {
            const int node = node0 + nb + n;
            if (node < N_NODES) {
                const float ax = acc[n].x, ay = acc[n].y;
                const float sx = ax * fast_rcp(1.0f + __expf(-ax));
                const float sy = ay * fast_rcp(1.0f + __expf(-ay));
                hhf[(size_t)node * 64 + lane] = h22u(__floats2half2_rn(sx, sy));
            }
        }
    } else if (b < OFF5) {
        const int n16 = NUM_GRAPHS * C_H / 4;
        const int stride = OUTZBLK * 256;
        for (int i = (b - OFF4) * 256 + t; i < n16; i += stride)
            outz[i] = make_uint4(0u, 0u, 0u, 0u);
    } else {
        if (t < NBUCK) bcur[t] = 0;
    }
}

// ---------------- bucketed CSR build ---------------------------------------------------------
__global__ __launch_bounds__(256) void bscatter_kernel(
        const int* __restrict__ row, const int* __restrict__ col,
        const float* __restrict__ pos, int* __restrict__ bcur, uint2* __restrict__ ebuf) {
    __shared__ int lhist[NBUCK];
    __shared__ int lcur[NBUCK];
    const int t = threadIdx.x;
    const int e0 = blockIdx.x * SCAT_BLK_EDGES;
    for (int i = t; i < NBUCK; i += 256) lhist[i] = 0;
    __syncthreads();

    int myb[8];
    uint2 myrec[8];
#pragma unroll
    for (int s = 0; s < 8; ++s) {
        const int e = e0 + s * 256 + t;
        if (e < N_EDGES) {
            const int r = __builtin_nontemporal_load(&row[e]);
            const int c = __builtin_nontemporal_load(&col[e]);
            const float dx = pos[r * 3 + 0] - pos[c * 3 + 0];
            const float dy = pos[r * 3 + 1] - pos[c * 3 + 1];
            const float dz = pos[r * 3 + 2] - pos[c * 3 + 2];
            const float d = sqrtf(dx * dx + dy * dy + dz * dz);
            int bin = (int)(d * TAB_SCALE);
            bin = bin < TAB_BINS - 1 ? bin : TAB_BINS - 1;
            myb[s] = c >> 8;
            myrec[s] = make_uint2((unsigned int)r | ((unsigned int)c << 16),
                                  (unsigned int)bin);
            atomicAdd(&lhist[myb[s]], 1);
        } else {
            myb[s] = -1;
        }
    }
    __syncthreads();
    for (int i = t; i < NBUCK; i += 256)
        lcur[i] = (lhist[i] > 0) ? atomicAdd(&bcur[i], lhist[i]) : 0;
    __syncthreads();
#pragma unroll
    for (int s = 0; s < 8; ++s) {
        if (myb[s] >= 0) {
            const int p = atomicAdd(&lcur[myb[s]], 1);
            ebuf[(size_t)myb[s] * REGION_CAP + p] = myrec[s];
        }
    }
}

__global__ __launch_bounds__(256) void bsort_kernel(
        const uint2* __restrict__ ebuf, const int* __restrict__ bcur,
        uint2* __restrict__ rcb) {
    __shared__ uint2 se[REGION_CAP];   // 48 KB
    __shared__ int lhist[256];
    __shared__ int lcur[256];
    __shared__ int csc[256];
    const int b = blockIdx.x;
    const int t = threadIdx.x;
    csc[t] = (t < NBUCK) ? bcur[t] : 0;
    __syncthreads();
    for (int d = 1; d < 256; d <<= 1) {
        const int x = (t >= d) ? csc[t - d] : 0;
        __syncthreads();
        csc[t] += x;
        __syncthreads();
    }
    const int dbase = (b == 0) ? 0 : csc[b - 1];
    const int n = bcur[b];

    const unsigned long long* src = (const unsigned long long*)(ebuf + (size_t)b * REGION_CAP);
    for (int i = t; i < n; i += 256) {
        const unsigned long long raw = __builtin_nontemporal_load(&src[i]);
        se[i] = make_uint2((unsigned int)raw, (unsigned int)(raw >> 32));
    }
    lhist[t] = 0;
    __syncthreads();
    for (int i = t; i < n; i += 256)
        atomicAdd(&lhist[(se[i].x >> 16) & 255u], 1);
    __syncthreads();
    int v = lhist[t];
    int sv = v;
    lcur[t] = v;
    __syncthreads();
    for (int d = 1; d < 256; d <<= 1) {
        const int x = (t >= d) ? lcur[t - d] : 0;
        __syncthreads();
        lcur[t] += x;
        __syncthreads();
        sv = lcur[t];
    }
    __syncthreads();
    lcur[t] = sv - v;  // exclusive
    __syncthreads();
    for (int i = t; i < n; i += 256) {
        const uint2 e = se[i];
        const int dst = atomicAdd(&lcur[(e.x >> 16) & 255u], 1);
        rcb[dbase + dst] = e;
    }
}

// ---------------- edge-parallel gather-aggregate (scalar meta, depth-4, XCD swizzle) --------
// Streaming data (rcb) read nontemporally, interior flushes stored nontemporally: preserve
// L2 capacity for the random h-gather + radial table.
__global__ __launch_bounds__(256) void aggregate_kernel(
        const unsigned int* __restrict__ hhf, const uint2* __restrict__ rcb,
        const unsigned int* __restrict__ tabh, unsigned int* __restrict__ aggh) {
    const int bid = blockIdx.x;
    const int xcd = bid & 7, ix = bid >> 3;
    const int qq = NAGG >> 3, rr = NAGG & 7;   // 390, 5
    const int blk = (xcd < rr ? xcd * (qq + 1) : rr * (qq + 1) + (xcd - rr) * qq) + ix;
    const int t = threadIdx.x;
    const int lane = t & 63;
    const int wv = __builtin_amdgcn_readfirstlane(t >> 6);
    const size_t base = (size_t)(blk * 4 + wv) * WEDGES;
    const unsigned long long* rcb64 = (const unsigned long long*)rcb;

    const __half2 hzero = __floats2half2_rn(0.0f, 0.0f);

    unsigned int huA[8], huB[8], huC[8], huD[8];
    unsigned int tvA[8], tvB[8], tvC[8], tvD[8];
    int colA[8], colB[8], colC[8], colD[8];
    __half2 acc2 = hzero;
    float2 accf = make_float2(0.0f, 0.0f);
    int sCur;
    bool first = true;

#define LOADG(g, HU, TV, CO)                                                  \
    {                                                                         \
        _Pragma("unroll")                                                     \
        for (int u = 0; u < 8; ++u) {                                         \
            const unsigned long long mraw =                                   \
                __builtin_nontemporal_load(&rcb64[base + (g) * 8 + u]);       \
            const unsigned int rcu =                                          \
                __builtin_amdgcn_readfirstlane((unsigned int)mraw);           \
            const int sBin =                                                  \
                __builtin_amdgcn_readfirstlane((int)(mraw >> 32));            \
            const int sRow = (int)(rcu & 0xffffu);                            \
            CO[u] = (int)(rcu >> 16);                                         \
            HU[u] = hhf[(size_t)sRow * 64 + lane];                            \
            TV[u] = tabh[(size_t)sBin * 64 + lane];                           \
        }                                                                     \
    }

#define COMPUTEG(HU, TV, CO)                                                  \
    {                                                                         \
        _Pragma("unroll")                                                     \
        for (int u = 0; u < 8; ++u) {                                         \
            if (CO[u] != sCur) {                                              \
                const float2 pf = __half22float2(acc2);                       \
                accf.x += pf.x; accf.y += pf.y; acc2 = hzero;                 \
                unsigned int* dst = &aggh[(size_t)sCur * 64 + lane];          \
                const unsigned int hv = h22u(__floats2half2_rn(accf.x, accf.y)); \
                if (first) {                                                  \
                    atomic_pk_add_h2(dst, hv);                                \
                    first = false;                                            \
                } else {                                                      \
                    __builtin_nontemporal_store(hv, dst);                     \
                }                                                             \
                accf.x = 0.0f; accf.y = 0.0f;                                 \
                sCur = CO[u];                                                 \
            }                                                                 \
            acc2 = __hfma2(u2h2(HU[u]), u2h2(TV[u]), acc2);                   \
        }                                                                     \
        const float2 pg = __half22float2(acc2);                               \
        accf.x += pg.x; accf.y += pg.y; acc2 = hzero;                         \
    }

    LOADG(0, huA, tvA, colA);
    LOADG(1, huB, tvB, colB);
    LOADG(2, huC, tvC, colC);
    LOADG(3, huD, tvD, colD);
    sCur = colA[0];
    COMPUTEG(huA, tvA, colA);
    LOADG(4, huA, tvA, colA);
    COMPUTEG(huB, tvB, colB);
    LOADG(5, huB, tvB, colB);
    COMPUTEG(huC, tvC, colC);
    LOADG(6, huC, tvC, colC);
    COMPUTEG(huD, tvD, colD);
    LOADG(7, huD, tvD, colD);
    COMPUTEG(huA, tvA, colA);
    COMPUTEG(huB, tvB, colB);
    COMPUTEG(huC, tvC, colC);
    COMPUTEG(huD, tvD, colD);

    {
        unsigned int* dst = &aggh[(size_t)sCur * 64 + lane];
        atomic_pk_add_h2(dst, h22u(__floats2half2_rn(accf.x, accf.y)));
    }
#undef LOADG
#undef COMPUTEG
}

// ---------------- node via MFMA: h' = g*lrelu((h+agg)@Wn + bn)/sqrt(1+eps)+be --------------
template <int POOL, int ZERO>
__global__ __launch_bounds__(256) void node_kernel(
        unsigned int* __restrict__ hhf, unsigned int* __restrict__ aggh,
        const uint4* __restrict__ Wnb, const float* __restrict__ bn,
        const float* __restrict__ g, const float* __restrict__ be,
        const int* __restrict__ batch, float* __restrict__ out) {
    __shared__ unsigned short sA[32 * 136];   // 8704 B
    const int node0 = blockIdx.x * 32;
    const int t = threadIdx.x;
    const uint4* hh4 = (const uint4*)hhf;
    uint4* ag4 = (uint4*)aggh;
    for (int i = t; i < 32 * 16; i += 256) {
        const int n = i >> 4;
        const int pp = i & 15;
        const int node = node0 + n;
        uint4 hv, av;
        if (node < N_NODES) {
            hv = hh4[(size_t)node * 16 + pp];
            av = ag4[(size_t)node * 16 + pp];
            if (ZERO) ag4[(size_t)node * 16 + pp] = make_uint4(0u, 0u, 0u, 0u);
        } else {
            hv = make_uint4(0u, 0u, 0u, 0u);
            av = hv;
        }
        uint4 sv;
        sv.x = h22u(__hadd2(u2h2(hv.x), u2h2(av.x)));
        sv.y = h22u(__hadd2(u2h2(hv.y), u2h2(av.y)));
        sv.z = h22u(__hadd2(u2h2(hv.z), u2h2(av.z)));
        sv.w = h22u(__hadd2(u2h2(hv.w), u2h2(av.w)));
        *(uint4*)&sA[n * 136 + 8 * pp] = sv;
    }
    __syncthreads();
    const int lane = t & 63;
    const int wv = t >> 6;
    const int q = lane >> 4;
    const int r = lane & 15;
    const int ct0 = 2 * wv, ct1 = 2 * wv + 1;
    const int c0 = ct0 * 16 + r, c1 = ct1 * 16 + r;
    const float bn0 = bn[c0], bn1 = bn[c1];
    f32x4_t acc00 = {bn0, bn0, bn0, bn0};
    f32x4_t acc01 = {bn1, bn1, bn1, bn1};
    f32x4_t acc10 = {bn0, bn0, bn0, bn0};
    f32x4_t acc11 = {bn1, bn1, bn1, bn1};
#pragma unroll
    for (int kc = 0; kc < 4; ++kc) {
        const half8_t a0 = __builtin_bit_cast(half8_t,
            *(const uint4*)&sA[(size_t)r * 136 + kc * 32 + 8 * q]);
        const half8_t a1 = __builtin_bit_cast(half8_t,
            *(const uint4*)&sA[(size_t)(16 + r) * 136 + kc * 32 + 8 * q]);
        const half8_t b0 = __builtin_bit_cast(half8_t, Wnb[(kc * 8 + ct0) * 64 + lane]);
        const half8_t b1 = __builtin_bit_cast(half8_t, Wnb[(kc * 8 + ct1) * 64 + lane]);
        acc00 = __builtin_amdgcn_mfma_f32_16x16x32_f16(a0, b0, acc00, 0, 0, 0);
        acc01 = __builtin_amdgcn_mfma_f32_16x16x32_f16(a0, b1, acc01, 0, 0, 0);
        acc10 = __builtin_amdgcn_mfma_f32_16x16x32_f16(a1, b0, acc10, 0, 0, 0);
        acc11 = __builtin_amdgcn_mfma_f32_16x16x32_f16(a1, b1, acc11, 0, 0, 0);
    }
    const float inv = 0.9999950000374997f;  // 1/sqrt(1+1e-5)
    const float gv0 = g[c0] * inv, gv1 = g[c1] * inv;
    const float be0 = be[c0], be1 = be[c1];
    if (POOL == 0) {
        unsigned short* hp = (unsigned short*)hhf;
#pragma unroll
        for (int rt = 0; rt < 2; ++rt) {
            const f32x4_t aA = rt ? acc10 : acc00;
            const f32x4_t aB = rt ? acc11 : acc01;
#pragma unroll
            for (int i = 0; i < 4; ++i) {
                const int node = node0 + rt * 16 + 4 * q + i;
                if (node < N_NODES) {
                    float v0 = aA[i]; v0 = v0 > 0.0f ? v0 : LRELU_SLOPE * v0;
                    float v1 = aB[i]; v1 = v1 > 0.0f ? v1 : LRELU_SLOPE * v1;
                    hp[(size_t)node * C_H + c0] =
                        __builtin_bit_cast(unsigned short, (_Float16)fmaf(gv0, v0, be0));
                    hp[(size_t)node * C_H + c1] =
                        __builtin_bit_cast(unsigned short, (_Float16)fmaf(gv1, v1, be1));
                }
            }
        }
    } else {
        // fused global_add_pool (batch sorted; this lane's nodes visited ascending)
        float pacc0 = 0.0f, pacc1 = 0.0f;
        int curb = -1;
#pragma unroll
        for (int rt = 0; rt < 2; ++rt) {
            const f32x4_t aA = rt ? acc10 : acc00;
            const f32x4_t aB = rt ? acc11 : acc01;
#pragma unroll
            for (int i = 0; i < 4; ++i) {
                const int node = node0 + rt * 16 + 4 * q + i;
                if (node < N_NODES) {
                    float v0 = aA[i]; v0 = v0 > 0.0f ? v0 : LRELU_SLOPE * v0;
                    float v1 = aB[i]; v1 = v1 > 0.0f ? v1 : LRELU_SLOPE * v1;
                    const float o0 = fmaf(gv0, v0, be0);
                    const float o1 = fmaf(gv1, v1, be1);
                    const int bb = batch[node];
                    if (bb != curb) {
                        if (curb >= 0) {
                            atomicAdd(&out[curb * C_H + c0], pacc0);
                            atomicAdd(&out[curb * C_H + c1], pacc1);
                        }
                        pacc0 = 0.0f; pacc1 = 0.0f;
                        curb = bb;
                    }
                    pacc0 += o0;
                    pacc1 += o1;
                }
            }
        }
        if (curb >= 0) {
            atomicAdd(&out[curb * C_H + c0], pacc0);
            atomicAdd(&out[curb * C_H + c1], pacc1);
        }
    }
}

extern "C" void kernel_launch(void* const* d_in, const int* in_sizes, int n_in,
                              void* d_out, int out_size, void* d_ws, size_t ws_size,
                              hipStream_t stream) {
    const float* x     = (const float*)d_in[0];
    const float* pos   = (const float*)d_in[1];
    const int*   eidx  = (const int*)d_in[2];
    const int*   batch = (const int*)d_in[3];
    const float* W_lin = (const float*)d_in[4];
    const float* b_lin = (const float*)d_in[5];

    unsigned int* aggh = (unsigned int*)d_ws;                          // 12.8 MB (half2)
    unsigned int* hhf  = aggh + (size_t)N_NODES * 64;                  // 12.8 MB
    unsigned int* Wnh  = hhf + (size_t)N_NODES * 64;                   // 3 * 32 KB (B frags)
    unsigned int* tabh = Wnh + 3 * C_H * 64;                           // 3 * 0.5 MB
    int* bcur = (int*)(tabh + 3 * (size_t)TAB_BINS * 64);              // 196
    uintptr_t p = (uintptr_t)(bcur + NBUCK);
    p = (p + 15) & ~(uintptr_t)15;
    uint2* ebuf = (uint2*)p;                                           // 9.6 MB
    uint2* rcb  = ebuf + (size_t)NBUCK * REGION_CAP;                   // 6.4 MB

    const int* row = eidx;
    const int* col = eidx + N_EDGES;

    // setup: 3 tables + 3 Wn frag-swizzles + agg zero + lin0 + out zero + bcur zero
    hipLaunchKernelGGL(setup_kernel, dim3(SETUP_GRID), dim3(256), 0, stream,
                       (const float*)d_in[6],  (const float*)d_in[7],
                       (const float*)d_in[12], (const float*)d_in[13],
                       (const float*)d_in[18], (const float*)d_in[19],
                       (const float*)d_in[8],  (const float*)d_in[14],
                       (const float*)d_in[20],
                       x, W_lin, b_lin,
                       tabh, Wnh, (uint4*)aggh, hhf, (uint4*)d_out, bcur);

    // bucketed CSR build
    hipLaunchKernelGGL(bscatter_kernel,
                       dim3((N_EDGES + SCAT_BLK_EDGES - 1) / SCAT_BLK_EDGES), dim3(256),
                       0, stream, row, col, pos, bcur, ebuf);
    hipLaunchKernelGGL(bsort_kernel, dim3(NBUCK), dim3(256), 0, stream,
                       ebuf, bcur, rcb);

    for (int l = 0; l < 3; ++l) {
        const float* bn = (const float*)d_in[6 + l * 6 + 3];
        const float* g  = (const float*)d_in[6 + l * 6 + 4];
        const float* be = (const float*)d_in[6 + l * 6 + 5];
        unsigned int* tab_l = tabh + (size_t)l * TAB_BINS * 64;
        const uint4* Wnb_l = (const uint4*)Wnh + (size_t)l * 2048;

        hipLaunchKernelGGL(aggregate_kernel, dim3(NAGG), dim3(256), 0, stream,
                           hhf, rcb, tab_l, aggh);
        if (l < 2) {
            hipLaunchKernelGGL(HIP_KERNEL_NAME(node_kernel<0, 1>),
                               dim3((N_NODES + 31) / 32), dim3(256), 0, stream,
                               hhf, aggh, Wnb_l, bn, g, be, batch, (float*)d_out);
        } else {
            hipLaunchKernelGGL(HIP_KERNEL_NAME(node_kernel<1, 0>),
                               dim3((N_NODES + 31) / 32), dim3(256), 0, stream,
                               hhf, aggh, Wnb_l, bn, g, be, batch, (float*)d_out);
        }
    }
}